// Round 1
// baseline (683.663 us; speedup 1.0000x reference)
//
#include <hip/hip_runtime.h>
#include <cstdint>

using bf16x8 = __attribute__((ext_vector_type(8))) __bf16;
using f32x4  = __attribute__((ext_vector_type(4))) float;
using s16x8  = __attribute__((ext_vector_type(8))) short;
using s16x4  = __attribute__((ext_vector_type(4))) short;

#define DI static __device__ __forceinline__

DI short f2bf(float f) {
  unsigned u = __float_as_uint(f);
  u = (u + 0x7fffu + ((u >> 16) & 1u)) >> 16;
  return (short)u;
}

DI void gload16(const short* g, short* l) {
  __builtin_amdgcn_global_load_lds((const __attribute__((address_space(1))) unsigned*)g,
                                   (__attribute__((address_space(3))) unsigned*)l, 16, 0, 0);
}

DI f32x4 mfma16(bf16x8 a, bf16x8 b, f32x4 c) {
  return __builtin_amdgcn_mfma_f32_16x16x32_bf16(a, b, c, 0, 0, 0);
}

// ---------------- weight prep ----------------
__global__ void k_transpose(const float* __restrict__ src, short* __restrict__ dst,
                            int K, int N) {
  int idx = blockIdx.x * 256 + threadIdx.x;   // over N*K, dst[n][k] = src[k][n]
  if (idx >= N * K) return;
  int n = idx / K, k = idx - n * K;
  dst[idx] = f2bf(src[(size_t)k * N + n]);
}

__global__ void k_prep_qkv(const float* __restrict__ w, const float* __restrict__ b,
                           short* __restrict__ wt, float* __restrict__ bp) {
  int idx = blockIdx.x * 256 + threadIdx.x;   // 768*256
  if (idx >= 768 * 256) return;
  int jn = idx >> 8;        // new col: q*256 + h*32 + d
  int k  = idx & 255;
  int q = jn >> 8, rest = jn & 255, h = rest >> 5, d = rest & 31;
  int jo = h * 96 + d * 3 + q;               // original col: h*(HD*3)+d*3+q
  wt[idx] = f2bf(w[(size_t)k * 768 + jo]);
  if (k == 0) bp[jn] = b[jo];
}

// ---------------- LN1 + window permute ----------------
__global__ __launch_bounds__(256) void k_ln1(const float* __restrict__ x,
    const float* __restrict__ g, const float* __restrict__ b, short* __restrict__ xw) {
  int w = threadIdx.x >> 6, lane = threadIdx.x & 63;
  int row = blockIdx.x * 4 + w;
  const float4 v = *(const float4*)(x + (size_t)row * 256 + lane * 4);
  float s = v.x + v.y + v.z + v.w;
  float q = v.x * v.x + v.y * v.y + v.z * v.z + v.w * v.w;
  #pragma unroll
  for (int m = 32; m >= 1; m >>= 1) { s += __shfl_xor(s, m); q += __shfl_xor(q, m); }
  float mean = s * (1.f / 256.f);
  float var  = q * (1.f / 256.f) - mean * mean;
  float r = rsqrtf(var + 1e-5f);
  const float4 gv = *(const float4*)(g + lane * 4);
  const float4 bv = *(const float4*)(b + lane * 4);
  int bb = row >> 12, rem = row & 4095, rr = rem >> 6, cc = rem & 63;
  int winw = (rr & 7) * 8 + (cc & 7);        // h2i*8 + w2i
  int tokw = (rr >> 3) * 8 + (cc >> 3);      // ws1*8 + ws2
  int wrow = bb * 4096 + winw * 64 + tokw;
  s16x4 o;
  o[0] = f2bf((v.x - mean) * r * gv.x + bv.x);
  o[1] = f2bf((v.y - mean) * r * gv.y + bv.y);
  o[2] = f2bf((v.z - mean) * r * gv.z + bv.z);
  o[3] = f2bf((v.w - mean) * r * gv.w + bv.w);
  *(s16x4*)(xw + (size_t)wrow * 256 + lane * 4) = o;
}

// ---------------- GEMM: C = A(M x K) * BT(N x K)^T, fused epilogues ----------------
// EPI 0: +bias, scale Q, split-write Q/K/V bf16       (BM=128, BN=128)
// EPI 1: +bias +x residual (win->spatial) +LN2        (BM=64,  BN=256)
// EPI 2: +bias, exact GELU, bf16                      (BM=128, BN=128)
// EPI 3: +bias + x1 (read d_out), write d_out fp32    (BM=128, BN=128)
template<int BM, int BN, int EPI>
__global__ __launch_bounds__(256, 2) void k_gemm(
    const short* __restrict__ A, const short* __restrict__ BT, int K,
    const float* __restrict__ bias,
    short* __restrict__ o16, float* __restrict__ o32,
    const float* __restrict__ xres, short* __restrict__ y2,
    const float* __restrict__ g2, const float* __restrict__ b2,
    int chunk_off, int qstride, int ostride)
{
  constexpr int WR = BM / 64;
  __shared__ __align__(16) short As[BM * 64];
  __shared__ __align__(16) short Bs[BN * 64];
  const int tid = threadIdx.x, lane = tid & 63, w = tid >> 6;
  const int l15 = lane & 15, hi = lane >> 4, hi4 = hi * 4;
  const int wr = (WR == 2) ? (w >> 1) : 0;
  const int wc = (WR == 2) ? (w & 1) : w;
  const int bm0 = blockIdx.x * BM, bn0 = blockIdx.y * BN;
  const int mload = lane >> 3, kload = (lane & 7) * 8;
  f32x4 acc[4][4] = {};
  for (int kt = 0; kt < K; kt += 64) {
    #pragma unroll
    for (int i = 0; i < BM / 32; ++i) {
      int seg = w * (BM / 32) + i;
      gload16(A + (size_t)(bm0 + seg * 8 + mload) * K + kt + kload, As + seg * 512);
    }
    #pragma unroll
    for (int i = 0; i < BN / 32; ++i) {
      int seg = w * (BN / 32) + i;
      gload16(BT + (size_t)(bn0 + seg * 8 + mload) * K + kt + kload, Bs + seg * 512);
    }
    __syncthreads();
    bf16x8 af[4][2], bfr[4][2];
    #pragma unroll
    for (int m = 0; m < 4; ++m)
      #pragma unroll
      for (int s = 0; s < 2; ++s)
        af[m][s] = *(const bf16x8*)&As[(wr * 64 + m * 16 + l15) * 64 + s * 32 + hi * 8];
    #pragma unroll
    for (int n = 0; n < 4; ++n)
      #pragma unroll
      for (int s = 0; s < 2; ++s)
        bfr[n][s] = *(const bf16x8*)&Bs[(wc * 64 + n * 16 + l15) * 64 + s * 32 + hi * 8];
    #pragma unroll
    for (int m = 0; m < 4; ++m)
      #pragma unroll
      for (int n = 0; n < 4; ++n) {
        acc[m][n] = mfma16(af[m][0], bfr[n][0], acc[m][n]);
        acc[m][n] = mfma16(af[m][1], bfr[n][1], acc[m][n]);
      }
    __syncthreads();
  }

  if constexpr (EPI == 0) {
    #pragma unroll
    for (int n = 0; n < 4; ++n) {
      int col = bn0 + wc * 64 + n * 16 + l15;
      float bia = bias[col];
      float sc = (col < 256) ? 0.17677669529663687f : 1.0f;
      short* dst = o16 + (size_t)(col >> 8) * qstride + (col & 255);
      #pragma unroll
      for (int m = 0; m < 4; ++m)
        #pragma unroll
        for (int j = 0; j < 4; ++j) {
          int row = bm0 + wr * 64 + m * 16 + hi4 + j;
          dst[(size_t)row * 256] = f2bf((acc[m][n][j] + bia) * sc);
        }
    }
  }

  if constexpr (EPI == 1) {
    __shared__ float redS[64 * 4];
    __shared__ float redQ[64 * 4];
    int srow[4][4];
    #pragma unroll
    for (int m = 0; m < 4; ++m)
      #pragma unroll
      for (int j = 0; j < 4; ++j) {
        int wrow = chunk_off + bm0 + m * 16 + hi4 + j;
        int bb = wrow >> 12, rem = wrow & 4095, win = rem >> 6, tok = rem & 63;
        int rsp = (tok >> 3) * 8 + (win >> 3);
        int csp = (tok & 7) * 8 + (win & 7);
        srow[m][j] = bb * 4096 + rsp * 64 + csp;
      }
    float s1[4][4], s2[4][4];
    #pragma unroll
    for (int m = 0; m < 4; ++m)
      #pragma unroll
      for (int j = 0; j < 4; ++j) { s1[m][j] = 0.f; s2[m][j] = 0.f; }
    #pragma unroll
    for (int m = 0; m < 4; ++m)
      #pragma unroll
      for (int n = 0; n < 4; ++n) {
        int col = bn0 + wc * 64 + n * 16 + l15;
        float bia = bias[col];
        #pragma unroll
        for (int j = 0; j < 4; ++j) {
          float val = acc[m][n][j] + bia + xres[(size_t)srow[m][j] * 256 + col];
          acc[m][n][j] = val;
          s1[m][j] += val; s2[m][j] += val * val;
        }
      }
    #pragma unroll
    for (int m = 0; m < 4; ++m)
      #pragma unroll
      for (int j = 0; j < 4; ++j) {
        float a = s1[m][j], bq = s2[m][j];
        #pragma unroll
        for (int mk = 1; mk < 16; mk <<= 1) { a += __shfl_xor(a, mk); bq += __shfl_xor(bq, mk); }
        s1[m][j] = a; s2[m][j] = bq;
      }
    if (l15 == 0) {
      #pragma unroll
      for (int m = 0; m < 4; ++m)
        #pragma unroll
        for (int j = 0; j < 4; ++j) {
          int rl = m * 16 + hi4 + j;
          redS[rl * 4 + wc] = s1[m][j];
          redQ[rl * 4 + wc] = s2[m][j];
        }
    }
    __syncthreads();
    #pragma unroll
    for (int m = 0; m < 4; ++m)
      #pragma unroll
      for (int j = 0; j < 4; ++j) {
        int rl = m * 16 + hi4 + j;
        float S = redS[rl * 4] + redS[rl * 4 + 1] + redS[rl * 4 + 2] + redS[rl * 4 + 3];
        float Q = redQ[rl * 4] + redQ[rl * 4 + 1] + redQ[rl * 4 + 2] + redQ[rl * 4 + 3];
        float mean = S * (1.f / 256.f);
        float var  = Q * (1.f / 256.f) - mean * mean;
        float rstd = rsqrtf(var + 1e-5f);
        int sr = srow[m][j];
        int lrow = sr - chunk_off;
        #pragma unroll
        for (int n = 0; n < 4; ++n) {
          int col = bn0 + wc * 64 + n * 16 + l15;
          float val = acc[m][n][j];
          o32[(size_t)sr * 256 + col] = val;
          float y = (val - mean) * rstd * g2[col] + b2[col];
          y2[(size_t)lrow * 256 + col] = f2bf(y);
        }
      }
  }

  if constexpr (EPI == 2) {
    #pragma unroll
    for (int n = 0; n < 4; ++n) {
      int col = bn0 + wc * 64 + n * 16 + l15;
      float bia = bias[col];
      #pragma unroll
      for (int m = 0; m < 4; ++m)
        #pragma unroll
        for (int j = 0; j < 4; ++j) {
          int row = bm0 + wr * 64 + m * 16 + hi4 + j;
          float val = acc[m][n][j] + bia;
          float ge = 0.5f * val * (1.f + erff(val * 0.70710678118654752f));
          o16[(size_t)row * ostride + col] = f2bf(ge);
        }
    }
  }

  if constexpr (EPI == 3) {
    #pragma unroll
    for (int n = 0; n < 4; ++n) {
      int col = bn0 + wc * 64 + n * 16 + l15;
      float bia = bias[col];
      #pragma unroll
      for (int m = 0; m < 4; ++m)
        #pragma unroll
        for (int j = 0; j < 4; ++j) {
          int row = bm0 + wr * 64 + m * 16 + hi4 + j;
          size_t ix = (size_t)row * 256 + col;
          float prev = o32[ix];
          o32[ix] = acc[m][n][j] + bia + prev;
        }
    }
  }
}

// ---------------- window attention: one block per (window, head) ----------------
__global__ __launch_bounds__(256, 2) void k_attn(
    const short* __restrict__ Q, const short* __restrict__ Kb,
    const short* __restrict__ V, short* __restrict__ O)
{
  __shared__ __align__(16) short Ks[64 * 72];
  __shared__ __align__(16) short VT[32 * 72];
  __shared__ __align__(16) short Ps[64 * 72];
  const int head = blockIdx.x & 7, win = blockIdx.x >> 3;
  const int tid = threadIdx.x, lane = tid & 63, w = tid >> 6;
  const int l15 = lane & 15, hi = lane >> 4, hi4 = hi * 4;
  const size_t base = (size_t)win * 16384 + head * 32;
  {
    int kk = tid >> 2, db = (tid & 3) * 8;
    s16x8 kv = *(const s16x8*)(Kb + base + (size_t)kk * 256 + db);
    *(s16x8*)&Ks[kk * 72 + db] = kv;
    s16x8 vv = *(const s16x8*)(V + base + (size_t)kk * 256 + db);
    #pragma unroll
    for (int i = 0; i < 8; ++i) VT[(db + i) * 72 + kk] = vv[i];
  }
  bf16x8 aq = *(const bf16x8*)(Q + base + (size_t)(w * 16 + l15) * 256 + hi * 8);
  __syncthreads();
  f32x4 zero = {0.f, 0.f, 0.f, 0.f};
  f32x4 s[4];
  #pragma unroll
  for (int t = 0; t < 4; ++t) {
    bf16x8 bk = *(const bf16x8*)&Ks[(t * 16 + l15) * 72 + hi * 8];
    s[t] = mfma16(aq, bk, zero);
  }
  float rs[4];
  #pragma unroll
  for (int j = 0; j < 4; ++j) {
    float m = fmaxf(fmaxf(s[0][j], s[1][j]), fmaxf(s[2][j], s[3][j]));
    #pragma unroll
    for (int mk = 1; mk < 16; mk <<= 1) m = fmaxf(m, __shfl_xor(m, mk));
    float sum = 0.f;
    #pragma unroll
    for (int t = 0; t < 4; ++t) { float p = __expf(s[t][j] - m); s[t][j] = p; sum += p; }
    #pragma unroll
    for (int mk = 1; mk < 16; mk <<= 1) sum += __shfl_xor(sum, mk);
    rs[j] = 1.f / sum;
  }
  #pragma unroll
  for (int t = 0; t < 4; ++t)
    #pragma unroll
    for (int j = 0; j < 4; ++j)
      Ps[(w * 16 + hi4 + j) * 72 + t * 16 + l15] = f2bf(s[t][j]);
  __syncthreads();
  f32x4 o[2] = {{0.f,0.f,0.f,0.f}, {0.f,0.f,0.f,0.f}};
  #pragma unroll
  for (int ks = 0; ks < 2; ++ks) {
    bf16x8 ap = *(const bf16x8*)&Ps[(w * 16 + l15) * 72 + ks * 32 + hi * 8];
    #pragma unroll
    for (int dt = 0; dt < 2; ++dt) {
      bf16x8 bv = *(const bf16x8*)&VT[(dt * 16 + l15) * 72 + ks * 32 + hi * 8];
      o[dt] = mfma16(ap, bv, o[dt]);
    }
  }
  #pragma unroll
  for (int dt = 0; dt < 2; ++dt)
    #pragma unroll
    for (int j = 0; j < 4; ++j)
      O[(size_t)(win * 64 + w * 16 + hi4 + j) * 256 + head * 32 + dt * 16 + l15] =
          f2bf(o[dt][j] * rs[j]);
}

// ---------------- host ----------------
extern "C" void kernel_launch(void* const* d_in, const int* in_sizes, int n_in,
                              void* d_out, int out_size, void* d_ws, size_t ws_size,
                              hipStream_t stream) {
  const float* x     = (const float*)d_in[0];
  const float* ln1g  = (const float*)d_in[1];
  const float* ln1b  = (const float*)d_in[2];
  const float* qkvw  = (const float*)d_in[3];
  const float* qkvb  = (const float*)d_in[4];
  const float* projw = (const float*)d_in[5];
  const float* projb = (const float*)d_in[6];
  const float* ln2g  = (const float*)d_in[7];
  const float* ln2b  = (const float*)d_in[8];
  const float* w1    = (const float*)d_in[9];
  const float* b1    = (const float*)d_in[10];
  const float* w2    = (const float*)d_in[11];
  const float* b2    = (const float*)d_in[12];
  float* out = (float*)d_out;
  char* ws = (char*)d_ws;

  // workspace map (≈85.5 MB):
  short* qkvbuf = (short*)ws;                   // 3 x 16,777,216 B (Q|K|V chunk)
  short* ao     = (short*)(ws + 50331648);      // 16,777,216 B attn-out chunk
  short* y2     = (short*)(ws + 67108864);      // 16,777,216 B ln2-out chunk
  short* h1     = (short*)ws;                   // 67,108,864 B (reuses qkv+ao after K4)
  char*  wreg   = ws + 83886080;
  short* WqkvT  = (short*)wreg;                 // 393,216 B
  short* WprojT = (short*)(wreg + 393216);      // 131,072 B
  short* W1T    = (short*)(wreg + 524288);      // 524,288 B
  short* W2T    = (short*)(wreg + 1048576);     // 524,288 B
  float* qkvbp  = (float*)(wreg + 1572864);     // 3,072 B
  // LN1 output lives in the upper half of d_out (safe: clobbered only after consumed)
  short* xw = (short*)((char*)d_out + 67108864);

  k_prep_qkv<<<768, 256, 0, stream>>>(qkvw, qkvb, WqkvT, qkvbp);
  k_transpose<<<256, 256, 0, stream>>>(projw, WprojT, 256, 256);
  k_transpose<<<1024, 256, 0, stream>>>(w1, W1T, 256, 1024);
  k_transpose<<<1024, 256, 0, stream>>>(w2, W2T, 1024, 256);
  k_ln1<<<32768, 256, 0, stream>>>(x, ln1g, ln1b, xw);

  for (int c = 0; c < 4; ++c) {
    const short* Ac = xw + (size_t)c * 8388608;
    k_gemm<128, 128, 0><<<dim3(256, 6), 256, 0, stream>>>(
        Ac, WqkvT, 256, qkvbp, qkvbuf, nullptr, nullptr, nullptr, nullptr, nullptr,
        0, 8388608, 256);
    k_attn<<<4096, 256, 0, stream>>>(qkvbuf, qkvbuf + 8388608, qkvbuf + 16777216, ao);
    k_gemm<64, 256, 1><<<dim3(512, 1), 256, 0, stream>>>(
        ao, WprojT, 256, projb, nullptr, out, x, y2, ln2g, ln2b,
        c * 32768, 0, 256);
    k_gemm<128, 128, 2><<<dim3(256, 8), 256, 0, stream>>>(
        y2, W1T, 256, b1, h1, nullptr, nullptr, nullptr, nullptr, nullptr,
        0, 0, 1024);
    k_gemm<128, 128, 3><<<dim3(256, 2), 256, 0, stream>>>(
        h1, W2T, 1024, b2, nullptr, out + (size_t)c * 8388608, nullptr, nullptr,
        nullptr, nullptr, 0, 0, 256);
  }
}